// Round 11
// baseline (1090.257 us; speedup 1.0000x reference)
//
#include <hip/hip_runtime.h>

#define T_STEPS 512
#define B_SZ    64
#define DIN     128
#define DH      1024
#define DOUT    256
#define RNK     64
#define HID_ELEMS ((size_t)T_STEPS * B_SZ * DH)   // 33554432

typedef _Float16 h2  __attribute__((ext_vector_type(2)));
typedef _Float16 h8v __attribute__((ext_vector_type(8)));
typedef short    s8v __attribute__((ext_vector_type(8)));
typedef float    f4v __attribute__((ext_vector_type(4)));

// barrier that does NOT drain vmcnt: global stores / prefetch stay in flight
#define WGBAR() asm volatile("s_waitcnt lgkmcnt(0)\n\ts_barrier" ::: "memory")

static __device__ __forceinline__ unsigned short f2bf(float f) {
    unsigned u = __float_as_uint(f);
    unsigned r = (u + 0x7FFFu + ((u >> 16) & 1u)) >> 16;   // RNE
    return (unsigned short)r;
}

static __device__ __forceinline__ float rdlane(float v, int l) {
    return __uint_as_float(__builtin_amdgcn_readlane(__float_as_uint(v), l));
}

// ---------------------------------------------------------------------------
// K0: Wo fp32 -> bf16 into workspace (one-time, 512 KB)
// ---------------------------------------------------------------------------
__global__ __launch_bounds__(256) void k0_cvt(
    const float* __restrict__ Wo, unsigned short* __restrict__ Wo16)
{
    int i = (blockIdx.x * 256 + threadIdx.x) * 4;
    float4 v = *reinterpret_cast<const float4*>(&Wo[i]);
    ushort4 o;
    o.x = f2bf(v.x); o.y = f2bf(v.y); o.z = f2bf(v.z); o.w = f2bf(v.w);
    *reinterpret_cast<ushort4*>(&Wo16[i]) = o;
}

// ---------------------------------------------------------------------------
// K1: zi[tb, h] = sum_k x[tb,k] * Wi[h,k] + bh[h]   -> stored into hidden region
// ---------------------------------------------------------------------------
__global__ __launch_bounds__(256) void k1_zi(
    const float* __restrict__ x, const float* __restrict__ Wi,
    const float* __restrict__ bh, float* __restrict__ zi)
{
    __shared__ float At[64][68];
    __shared__ float Bt[64][68];
    const int m0 = blockIdx.y * 64;
    const int n0 = blockIdx.x * 64;
    const int tid = threadIdx.x;
    const int tx = tid & 15, ty = tid >> 4;
    float acc[4][4] = {};

    for (int kc = 0; kc < DIN; kc += 64) {
        #pragma unroll
        for (int i = 0; i < 4; ++i) {
            int idx = tid + i * 256;
            int row = idx >> 4;
            int c4  = idx & 15;
            float4 v = *reinterpret_cast<const float4*>(&x[(size_t)(m0 + row) * DIN + kc + c4 * 4]);
            At[c4*4+0][row] = v.x; At[c4*4+1][row] = v.y;
            At[c4*4+2][row] = v.z; At[c4*4+3][row] = v.w;
        }
        #pragma unroll
        for (int i = 0; i < 4; ++i) {
            int idx = tid + i * 256;
            int row = idx >> 4;
            int c4  = idx & 15;
            float4 v = *reinterpret_cast<const float4*>(&Wi[(size_t)(n0 + row) * DIN + kc + c4 * 4]);
            Bt[c4*4+0][row] = v.x; Bt[c4*4+1][row] = v.y;
            Bt[c4*4+2][row] = v.z; Bt[c4*4+3][row] = v.w;
        }
        __syncthreads();
        #pragma unroll
        for (int k = 0; k < 64; ++k) {
            float4 a = *reinterpret_cast<const float4*>(&At[k][ty * 4]);
            float4 b = *reinterpret_cast<const float4*>(&Bt[k][tx * 4]);
            float av[4] = {a.x, a.y, a.z, a.w};
            float bv[4] = {b.x, b.y, b.z, b.w};
            #pragma unroll
            for (int i = 0; i < 4; ++i)
                #pragma unroll
                for (int j = 0; j < 4; ++j)
                    acc[i][j] = fmaf(av[i], bv[j], acc[i][j]);
        }
        __syncthreads();
    }
    float4 bias = *reinterpret_cast<const float4*>(&bh[n0 + tx * 4]);
    #pragma unroll
    for (int i = 0; i < 4; ++i) {
        float4 o;
        o.x = acc[i][0] + bias.x; o.y = acc[i][1] + bias.y;
        o.z = acc[i][2] + bias.z; o.w = acc[i][3] + bias.w;
        *reinterpret_cast<float4*>(&zi[(size_t)(m0 + ty * 4 + i) * DH + n0 + tx * 4]) = o;
    }
}

// ---------------------------------------------------------------------------
// K2 v4: fit weights under the 128-VGPR cap.
// 1024 threads (16 waves) per batch element; each thread owns ONE h element.
//   u[64] fp32  (64 VGPR)  = U[j][:]     -- expand, full precision
//   vh[32] fp16 (32 VGPR)  = V[lane][g*64 .. +64)  -- contract slice
// Wave g's contract slice == the h elements wave g itself computed -> the
// expand->contract handoff is wave-local (lgkmcnt only, NO barrier).
// One barrier per step; red double-buffered by t&1 to avoid the
// fast-writer-vs-slow-reader race across steps.
// ---------------------------------------------------------------------------
__global__ __launch_bounds__(1024, 1) void k2_rec(
    const float* __restrict__ U, const float* __restrict__ V,
    float* __restrict__ hid)
{
    __shared__ _Float16 h16[DH];       // 2 KB
    __shared__ float red[2][16][64];   // 8 KB, double-buffered
    const int b    = blockIdx.x;
    const int tid  = threadIdx.x;
    const int lane = tid & 63;
    const int g    = tid >> 6;          // wave id 0..15
    const int j    = tid;               // owned h element

    // ---- one-time: weights into registers (~96 VGPRs of state) ----
    float u[64];
    const float4* __restrict__ U4 = reinterpret_cast<const float4*>(U);
    #pragma unroll
    for (int q = 0; q < 16; ++q) {
        float4 a = U4[j * 16 + q];
        u[q*4+0]=a.x; u[q*4+1]=a.y; u[q*4+2]=a.z; u[q*4+3]=a.w;
    }
    h2 vh[32];                           // V[lane][g*64 + 2m .. +1]
    {
        const float2* __restrict__ vrow =
            reinterpret_cast<const float2*>(V + (size_t)lane * DH + g * 64);
        #pragma unroll
        for (int m = 0; m < 32; ++m) {
            float2 f = vrow[m];
            h2 p; p.x = (_Float16)f.x; p.y = (_Float16)f.y;
            vh[m] = p;
        }
    }

    float rv = 0.0f;                     // lane l holds r_l (h0 = 0 -> r = 0)
    size_t base = (size_t)b * DH;
    float z = hid[base + j];             // zi + bh for t = 0

    for (int t = 0; t < T_STEPS; ++t) {
        // expand: e_j = zi_j + sum_k r_k * U[j,k]  (fp32, 4 split chains)
        float e0 = z, e1 = 0.f, e2 = 0.f, e3 = 0.f;
        #pragma unroll
        for (int kk = 0; kk < 64; kk += 4) {
            float r0 = rdlane(rv, kk + 0);
            float r1 = rdlane(rv, kk + 1);
            float r2 = rdlane(rv, kk + 2);
            float r3 = rdlane(rv, kk + 3);
            e0 = fmaf(r0, u[kk + 0], e0);
            e1 = fmaf(r1, u[kk + 1], e1);
            e2 = fmaf(r2, u[kk + 2], e2);
            e3 = fmaf(r3, u[kk + 3], e3);
        }
        float h = fmaxf((e0 + e1) + (e2 + e3), 0.0f);

        // prefetch next zi; store h (both fire-and-forget across the barrier)
        size_t nbase = base + (size_t)B_SZ * DH;
        float nz = hid[nbase + j];       // t=511 reads out-region: unused, safe
        hid[base + j] = h;
        h16[j] = (_Float16)h;            // wave-local exchange

        asm volatile("s_waitcnt lgkmcnt(0)" ::: "memory");  // own-wave ds_write done

        // contract: wave g, lane k: a = sum_{jj in wave-g slice} h[jj]*V[k][jj]
        float a0 = 0.f, a1 = 0.f, a2 = 0.f, a3 = 0.f;
        const h8v* __restrict__ hp8 = reinterpret_cast<const h8v*>(&h16[g * 64]);
        #pragma unroll
        for (int q = 0; q < 8; ++q) {
            h8v hv = hp8[q];             // broadcast ds_read_b128
            h2 p0; p0.x = hv[0]; p0.y = hv[1];
            h2 p1; p1.x = hv[2]; p1.y = hv[3];
            h2 p2; p2.x = hv[4]; p2.y = hv[5];
            h2 p3; p3.x = hv[6]; p3.y = hv[7];
            a0 = __builtin_amdgcn_fdot2(p0, vh[q*4+0], a0, false);
            a1 = __builtin_amdgcn_fdot2(p1, vh[q*4+1], a1, false);
            a2 = __builtin_amdgcn_fdot2(p2, vh[q*4+2], a2, false);
            a3 = __builtin_amdgcn_fdot2(p3, vh[q*4+3], a3, false);
        }
        red[t & 1][g][lane] = (a0 + a1) + (a2 + a3);

        WGBAR();                         // the ONLY barrier per step

        const float* __restrict__ rr = &red[t & 1][0][0];
        float s0 = rr[ 0*64 + lane] + rr[ 1*64 + lane];
        float s1 = rr[ 2*64 + lane] + rr[ 3*64 + lane];
        float s2 = rr[ 4*64 + lane] + rr[ 5*64 + lane];
        float s3 = rr[ 6*64 + lane] + rr[ 7*64 + lane];
        float s4 = rr[ 8*64 + lane] + rr[ 9*64 + lane];
        float s5 = rr[10*64 + lane] + rr[11*64 + lane];
        float s6 = rr[12*64 + lane] + rr[13*64 + lane];
        float s7 = rr[14*64 + lane] + rr[15*64 + lane];
        rv = ((s0 + s1) + (s2 + s3)) + ((s4 + s5) + (s6 + s7));

        z = nz; base = nbase;
    }
}

// ---------------------------------------------------------------------------
// K3 v2: bf16 MFMA GEMM. out[32768,256] = hid @ Wo.T + bo.  (unchanged)
// ---------------------------------------------------------------------------
__global__ __launch_bounds__(256, 1) void k3_out(
    const float* __restrict__ hid, const unsigned short* __restrict__ Wo16,
    const float* __restrict__ bo, float* __restrict__ out)
{
    __shared__ unsigned short As[128][72];
    __shared__ unsigned short Bs[128][72];
    const int tid = threadIdx.x;
    const int w  = tid >> 6, l = tid & 63;
    const int wr = w >> 1,  wc = w & 1;
    const int m0 = blockIdx.x * 128;
    const int n0 = blockIdx.y * 128;
    const int fr = l & 15;
    const int fg = l >> 4;
    f4v acc[4][4] = {};

    for (int kc = 0; kc < DH; kc += 64) {
        __syncthreads();
        #pragma unroll
        for (int uu = 0; uu < 4; ++uu) {
            int u = tid + uu * 256;
            int row = u >> 3, ks = u & 7;
            const float4* src = reinterpret_cast<const float4*>(
                &hid[(size_t)(m0 + row) * DH + kc + ks * 8]);
            float4 a = src[0], bqq = src[1];
            s8v t;
            t[0] = (short)f2bf(a.x);  t[1] = (short)f2bf(a.y);
            t[2] = (short)f2bf(a.z);  t[3] = (short)f2bf(a.w);
            t[4] = (short)f2bf(bqq.x); t[5] = (short)f2bf(bqq.y);
            t[6] = (short)f2bf(bqq.z); t[7] = (short)f2bf(bqq.w);
            *reinterpret_cast<s8v*>(&As[row][ks * 8]) = t;
        }
        #pragma unroll
        for (int uu = 0; uu < 4; ++uu) {
            int u = tid + uu * 256;
            int row = u >> 3, ks = u & 7;
            s8v v = *reinterpret_cast<const s8v*>(
                &Wo16[(size_t)(n0 + row) * DH + kc + ks * 8]);
            *reinterpret_cast<s8v*>(&Bs[row][ks * 8]) = v;
        }
        __syncthreads();
        #pragma unroll
        for (int kk = 0; kk < 64; kk += 32) {
            s8v af[4], bf[4];
            #pragma unroll
            for (int i = 0; i < 4; ++i)
                af[i] = *reinterpret_cast<const s8v*>(&As[wr*64 + i*16 + fr][kk + fg*8]);
            #pragma unroll
            for (int i = 0; i < 4; ++i)
                bf[i] = *reinterpret_cast<const s8v*>(&Bs[wc*64 + i*16 + fr][kk + fg*8]);
            #pragma unroll
            for (int mi = 0; mi < 4; ++mi)
                #pragma unroll
                for (int ni = 0; ni < 4; ++ni)
                    acc[mi][ni] = __builtin_amdgcn_mfma_f32_16x16x32_bf16(
                        af[mi], bf[ni], acc[mi][ni], 0, 0, 0);
        }
    }
    #pragma unroll
    for (int ni = 0; ni < 4; ++ni) {
        int col = n0 + wc*64 + ni*16 + fr;
        float bias = bo[col];
        #pragma unroll
        for (int mi = 0; mi < 4; ++mi) {
            #pragma unroll
            for (int r = 0; r < 4; ++r) {
                int row = m0 + wr*64 + mi*16 + fg*4 + r;
                out[(size_t)row * DOUT + col] = acc[mi][ni][r] + bias;
            }
        }
    }
}

// ---------------------------------------------------------------------------
extern "C" void kernel_launch(void* const* d_in, const int* in_sizes, int n_in,
                              void* d_out, int out_size, void* d_ws, size_t ws_size,
                              hipStream_t stream)
{
    const float* x  = (const float*)d_in[0];
    const float* Wi = (const float*)d_in[1];
    const float* U  = (const float*)d_in[2];
    const float* V  = (const float*)d_in[3];
    const float* bh = (const float*)d_in[4];
    const float* Wo = (const float*)d_in[5];
    const float* bo = (const float*)d_in[6];
    float* hid  = (float*)d_out;              // hidden region, also zi staging
    float* outp = (float*)d_out + HID_ELEMS;  // output region
    unsigned short* Wo16 = (unsigned short*)d_ws;  // 512 KB

    k0_cvt<<<dim3(DOUT * DH / (256 * 4)), 256, 0, stream>>>(Wo, Wo16);
    k1_zi<<<dim3(DH / 64, (T_STEPS * B_SZ) / 64), 256, 0, stream>>>(x, Wi, bh, hid);
    k2_rec<<<dim3(B_SZ), 1024, 0, stream>>>(U, V, hid);
    k3_out<<<dim3((T_STEPS * B_SZ) / 128, DOUT / 128), 256, 0, stream>>>(hid, Wo16, bo, outp);
}